// Round 2
// baseline (150.088 us; speedup 1.0000x reference)
//
#include <hip/hip_runtime.h>
#include <hip/hip_cooperative_groups.h>
#include <math.h>

namespace cg = cooperative_groups;

#define NTOK 2048
#define CDIM 128
#define HHEADS 8
#define HDIM 16
#define NQW 32
#define NKW 128
#define PADW 48
#define CPD 16
#define BT 8

__device__ __forceinline__ float sigmoid_(float z){ return 1.0f/(1.0f+__expf(-z)); }
__device__ __forceinline__ float rdlane(float v, int l){
    return __int_as_float(__builtin_amdgcn_readlane(__float_as_int(v), l));
}

// ==================== FUSED cooperative kernel ====================
// grid = 256 blocks x 512 thr, 1 block/CU co-resident.
// Phase A: pair-bias (2 items/thread) + AdaLN/QKV token-per-wave (no LDS, no barriers)
// Phase B: local-window attention, 2 (ib,h) units per block (verified R0 body)
// Phase C: output gating stack token-per-wave (no LDS, no barriers)
__global__ __launch_bounds__(512, 2) void k_fused(
    const float* __restrict__ x, const float* __restrict__ s,
    const float* __restrict__ s_w,
    const float* __restrict__ gate_w, const float* __restrict__ gate_b,
    const float* __restrict__ skip_w,
    const float* __restrict__ q_w, const float* __restrict__ q_b,
    const float* __restrict__ k_w, const float* __restrict__ v_w,
    const float* __restrict__ pair, const float* __restrict__ pln_w,
    const float* __restrict__ pln_b, const float* __restrict__ pproj,
    const float* __restrict__ ogate_w, const float* __restrict__ oproj_w,
    const float* __restrict__ oout_w, const float* __restrict__ oout_b,
    float* __restrict__ qo, float* __restrict__ ko, float* __restrict__ vo,
    float* __restrict__ oo, float* __restrict__ bias, float* __restrict__ out)
{
    __shared__ float smem[2*8896];     // phase B only: 2 x (khs 2560 | vts 2112 | Pms 4224)
    const int tid = threadIdx.x;
    const int bid = blockIdx.x;
    cg::grid_group grid = cg::this_grid();

    // ---------------- Phase A1: pair bias, 2 items per thread ----------------
    #pragma unroll
    for (int rep = 0; rep < 2; ++rep) {
        const int idx = rep*131072 + bid*512 + tid;    // [0, 2048*128)
        const int qg = idx >> 7;
        const int j  = idx & 127;
        const int ib = qg >> 5;
        const int qr = qg & 31;
        const int kg = (ib << 5) - PADW + j;
        float outh[HHEADS] = {0,0,0,0,0,0,0,0};
        if (kg >= 0 && kg < NTOK) {
            const float* p = pair + ((size_t)qg * NTOK + kg) * CPD;
            float buf[CPD];
            float sum = 0.f, ssq = 0.f;
            #pragma unroll
            for (int c = 0; c < CPD; c += 4) {
                const float4 t4 = *(const float4*)(p + c);
                buf[c+0]=t4.x; buf[c+1]=t4.y; buf[c+2]=t4.z; buf[c+3]=t4.w;
                sum += t4.x+t4.y+t4.z+t4.w;
                ssq += t4.x*t4.x+t4.y*t4.y+t4.z*t4.z+t4.w*t4.w;
            }
            const float m  = sum * (1.0f/CPD);
            const float vr = ssq * (1.0f/CPD) - m*m;
            const float rs = rsqrtf(vr + 1e-5f);
            #pragma unroll
            for (int c = 0; c < CPD; ++c) {
                const float y = (buf[c]-m)*rs*pln_w[c] + pln_b[c];
                #pragma unroll
                for (int h = 0; h < HHEADS; ++h)
                    outh[h] = fmaf(y, pproj[c*HHEADS+h], outh[h]);
            }
        }
        float* bb = bias + ((size_t)(ib*HHEADS)*NQW + qr)*NKW + j;
        #pragma unroll
        for (int h = 0; h < HHEADS; ++h)
            bb[(size_t)h*NQW*NKW] = outh[h];
    }

    // ---------------- Phase A2: AdaLN + QKV, token-per-wave ----------------
    {
        const int tok = bid*8 + (tid>>6);
        const int L = tid & 63;
        const float2 xv = *(const float2*)(x + (size_t)tok*CDIM + 2*L);
        const float2 yv = *(const float2*)(s + (size_t)tok*CDIM + 2*L);
        float sx = xv.x+xv.y, sxx = xv.x*xv.x+xv.y*xv.y;
        float sy = yv.x+yv.y, syy = yv.x*yv.x+yv.y*yv.y;
        #pragma unroll
        for (int m = 1; m < 64; m <<= 1) {
            sx  += __shfl_xor(sx,  m, 64);
            sxx += __shfl_xor(sxx, m, 64);
            sy  += __shfl_xor(sy,  m, 64);
            syy += __shfl_xor(syy, m, 64);
        }
        const float inv = 1.0f/128.0f;
        const float mx = sx*inv, vx = sxx*inv - mx*mx;
        const float my = sy*inv, vy = syy*inv - my*my;
        const float rx = rsqrtf(vx+1e-5f), ry = rsqrtf(vy+1e-5f);
        const float2 swv = *(const float2*)(s_w + 2*L);
        const float a0  = (xv.x-mx)*rx,        a1  = (xv.y-mx)*rx;
        const float sn0 = (yv.x-my)*ry*swv.x,  sn1 = (yv.y-my)*ry*swv.y;

        // z_gate / z_skip: lane L owns output channels 2L, 2L+1
        float zg0=0,zg1=0,zs0=0,zs1=0;
        #pragma unroll 4
        for (int p = 0; p < 64; ++p) {
            const float ae = rdlane(sn0,p), ao = rdlane(sn1,p);
            const float2 g0 = *(const float2*)(gate_w + (size_t)(2*p  )*CDIM + 2*L);
            const float2 g1 = *(const float2*)(gate_w + (size_t)(2*p+1)*CDIM + 2*L);
            const float2 s0 = *(const float2*)(skip_w + (size_t)(2*p  )*CDIM + 2*L);
            const float2 s1 = *(const float2*)(skip_w + (size_t)(2*p+1)*CDIM + 2*L);
            zg0 = fmaf(ae,g0.x,zg0); zg1 = fmaf(ae,g0.y,zg1);
            zg0 = fmaf(ao,g1.x,zg0); zg1 = fmaf(ao,g1.y,zg1);
            zs0 = fmaf(ae,s0.x,zs0); zs1 = fmaf(ae,s0.y,zs1);
            zs0 = fmaf(ao,s1.x,zs0); zs1 = fmaf(ao,s1.y,zs1);
        }
        const float2 gbv = *(const float2*)(gate_b + 2*L);
        const float a2_0 = sigmoid_(zg0+gbv.x)*a0 + zs0;
        const float a2_1 = sigmoid_(zg1+gbv.y)*a1 + zs1;

        float zq0=0,zq1=0,zk0=0,zk1=0,zv0=0,zv1=0;
        #pragma unroll 4
        for (int p = 0; p < 64; ++p) {
            const float ae = rdlane(a2_0,p), ao = rdlane(a2_1,p);
            const float2 q0v = *(const float2*)(q_w + (size_t)(2*p  )*CDIM + 2*L);
            const float2 q1v = *(const float2*)(q_w + (size_t)(2*p+1)*CDIM + 2*L);
            const float2 k0v = *(const float2*)(k_w + (size_t)(2*p  )*CDIM + 2*L);
            const float2 k1v = *(const float2*)(k_w + (size_t)(2*p+1)*CDIM + 2*L);
            const float2 v0v = *(const float2*)(v_w + (size_t)(2*p  )*CDIM + 2*L);
            const float2 v1v = *(const float2*)(v_w + (size_t)(2*p+1)*CDIM + 2*L);
            zq0 = fmaf(ae,q0v.x,zq0); zq1 = fmaf(ae,q0v.y,zq1);
            zq0 = fmaf(ao,q1v.x,zq0); zq1 = fmaf(ao,q1v.y,zq1);
            zk0 = fmaf(ae,k0v.x,zk0); zk1 = fmaf(ae,k0v.y,zk1);
            zk0 = fmaf(ao,k1v.x,zk0); zk1 = fmaf(ao,k1v.y,zk1);
            zv0 = fmaf(ae,v0v.x,zv0); zv1 = fmaf(ae,v0v.y,zv1);
            zv0 = fmaf(ao,v1v.x,zv0); zv1 = fmaf(ao,v1v.y,zv1);
        }
        const float2 qbv = *(const float2*)(q_b + 2*L);
        *(float2*)(qo + (size_t)tok*CDIM + 2*L) = make_float2(zq0+qbv.x, zq1+qbv.y);
        *(float2*)(ko + (size_t)tok*CDIM + 2*L) = make_float2(zk0, zk1);
        *(float2*)(vo + (size_t)tok*CDIM + 2*L) = make_float2(zv0, zv1);
    }

    grid.sync();

    // ---------------- Phase B: attention, 2 units per block ----------------
    {
        const int u  = (bid<<1) | (tid>>8);    // (ib,h) unit 0..511
        const int t  = tid & 255;
        const int ib = u >> 3;
        const int h  = u & 7;
        float* khs = smem + (tid>>8)*8896;     // [128][20]
        float* vts = khs + 2560;               // [16][132]  (V^T)
        float* Pms = khs + 4672;               // [32][132]

        {   // stage: K row-major padded, V transposed
            const int jr  = t >> 1;
            const int d08 = (t & 1) * 8;
            const int kg  = ib*NQW - PADW + jr;
            float4 k0 = {0,0,0,0}, k1 = {0,0,0,0};
            float4 v0 = {0,0,0,0}, v1 = {0,0,0,0};
            if (kg >= 0 && kg < NTOK) {
                const float* sk = ko + (size_t)kg*CDIM + h*HDIM + d08;
                const float* sv = vo + (size_t)kg*CDIM + h*HDIM + d08;
                k0 = *(const float4*)sk;  k1 = *(const float4*)(sk+4);
                v0 = *(const float4*)sv;  v1 = *(const float4*)(sv+4);
            }
            *(float4*)&khs[jr*20 + d08]     = k0;
            *(float4*)&khs[jr*20 + d08 + 4] = k1;
            vts[(d08+0)*132 + jr] = v0.x;
            vts[(d08+1)*132 + jr] = v0.y;
            vts[(d08+2)*132 + jr] = v0.z;
            vts[(d08+3)*132 + jr] = v0.w;
            vts[(d08+4)*132 + jr] = v1.x;
            vts[(d08+5)*132 + jr] = v1.y;
            vts[(d08+6)*132 + jr] = v1.z;
            vts[(d08+7)*132 + jr] = v1.w;
        }
        __syncthreads();

        {   // QK^T + bias + softmax: thread = 2 q-rows x 8 k-cols
            const int rp = t >> 4;
            const int ln = t & 15;
            const int q0 = 2*rp;
            float4 qv[2][4];
            #pragma unroll
            for (int i = 0; i < 2; ++i) {
                const float4* qp = (const float4*)(qo + (size_t)(ib*NQW + q0 + i)*CDIM + h*HDIM);
                #pragma unroll
                for (int dq = 0; dq < 4; ++dq) qv[i][dq] = qp[dq];
            }
            const float* br = bias + ((size_t)(ib*HHEADS + h)*NQW + q0)*NKW;
            float acc[2][8];
            #pragma unroll
            for (int m2 = 0; m2 < 8; ++m2) {
                const int k = ln + 16*m2;
                const float4 c0 = *(const float4*)&khs[k*20];
                const float4 c1 = *(const float4*)&khs[k*20 + 4];
                const float4 c2 = *(const float4*)&khs[k*20 + 8];
                const float4 c3 = *(const float4*)&khs[k*20 + 12];
                #pragma unroll
                for (int i = 0; i < 2; ++i) {
                    float sdot = qv[i][0].x*c0.x;
                    sdot = fmaf(qv[i][0].y, c0.y, sdot);
                    sdot = fmaf(qv[i][0].z, c0.z, sdot);
                    sdot = fmaf(qv[i][0].w, c0.w, sdot);
                    sdot = fmaf(qv[i][1].x, c1.x, sdot);
                    sdot = fmaf(qv[i][1].y, c1.y, sdot);
                    sdot = fmaf(qv[i][1].z, c1.z, sdot);
                    sdot = fmaf(qv[i][1].w, c1.w, sdot);
                    sdot = fmaf(qv[i][2].x, c2.x, sdot);
                    sdot = fmaf(qv[i][2].y, c2.y, sdot);
                    sdot = fmaf(qv[i][2].z, c2.z, sdot);
                    sdot = fmaf(qv[i][2].w, c2.w, sdot);
                    sdot = fmaf(qv[i][3].x, c3.x, sdot);
                    sdot = fmaf(qv[i][3].y, c3.y, sdot);
                    sdot = fmaf(qv[i][3].z, c3.z, sdot);
                    sdot = fmaf(qv[i][3].w, c3.w, sdot);
                    acc[i][m2] = sdot*0.25f + br[(size_t)i*NKW + k];
                }
            }
            #pragma unroll
            for (int i = 0; i < 2; ++i) {
                float mx = acc[i][0];
                #pragma unroll
                for (int m2 = 1; m2 < 8; ++m2) mx = fmaxf(mx, acc[i][m2]);
                mx = fmaxf(mx, __shfl_xor(mx, 1, 64));
                mx = fmaxf(mx, __shfl_xor(mx, 2, 64));
                mx = fmaxf(mx, __shfl_xor(mx, 4, 64));
                mx = fmaxf(mx, __shfl_xor(mx, 8, 64));
                float sm = 0.f;
                #pragma unroll
                for (int m2 = 0; m2 < 8; ++m2) { acc[i][m2] = __expf(acc[i][m2]-mx); sm += acc[i][m2]; }
                sm += __shfl_xor(sm, 1, 64);
                sm += __shfl_xor(sm, 2, 64);
                sm += __shfl_xor(sm, 4, 64);
                sm += __shfl_xor(sm, 8, 64);
                const float invs = 1.0f / sm;
                #pragma unroll
                for (int m2 = 0; m2 < 8; ++m2)
                    Pms[(q0+i)*132 + ln + 16*m2] = acc[i][m2]*invs;
            }
        }
        __syncthreads();

        {   // PV: thread = (qr, d0); k-vectorized b128
            const int qr = t >> 3, d0 = t & 7;
            const float* pr  = &Pms[qr*132];
            const float* vp0 = &vts[d0*132];
            const float* vp1 = &vts[(d0+8)*132];
            float pa0 = 0.f, pa1 = 0.f;
            #pragma unroll
            for (int k4 = 0; k4 < 32; ++k4) {
                const float4 pm = *(const float4*)(pr  + 4*k4);
                const float4 u0 = *(const float4*)(vp0 + 4*k4);
                const float4 u1 = *(const float4*)(vp1 + 4*k4);
                pa0 = fmaf(pm.x, u0.x, pa0); pa0 = fmaf(pm.y, u0.y, pa0);
                pa0 = fmaf(pm.z, u0.z, pa0); pa0 = fmaf(pm.w, u0.w, pa0);
                pa1 = fmaf(pm.x, u1.x, pa1); pa1 = fmaf(pm.y, u1.y, pa1);
                pa1 = fmaf(pm.z, u1.z, pa1); pa1 = fmaf(pm.w, u1.w, pa1);
            }
            float* dst = oo + (size_t)(ib*NQW + qr)*CDIM + h*HDIM;
            dst[d0]   = pa0;
            dst[d0+8] = pa1;
        }
    }

    grid.sync();

    // ---------------- Phase C: gating stack, token-per-wave ----------------
    {
        const int tok = bid*8 + (tid>>6);
        const int L = tid & 63;
        const float2 ov = *(const float2*)(oo + (size_t)tok*CDIM + 2*L);

        float z0=0,z1=0;
        #pragma unroll 4
        for (int p = 0; p < 64; ++p) {
            const float ae = rdlane(ov.x,p), ao = rdlane(ov.y,p);
            const float2 w0 = *(const float2*)(ogate_w + (size_t)(2*p  )*CDIM + 2*L);
            const float2 w1 = *(const float2*)(ogate_w + (size_t)(2*p+1)*CDIM + 2*L);
            z0 = fmaf(ae,w0.x,z0); z1 = fmaf(ae,w0.y,z1);
            z0 = fmaf(ao,w1.x,z0); z1 = fmaf(ao,w1.y,z1);
        }
        const float g0 = sigmoid_(z0)*ov.x;
        const float g1 = sigmoid_(z1)*ov.y;

        float t0=0,t1=0;
        #pragma unroll 4
        for (int p = 0; p < 64; ++p) {
            const float ae = rdlane(g0,p), ao = rdlane(g1,p);
            const float2 w0 = *(const float2*)(oproj_w + (size_t)(2*p  )*CDIM + 2*L);
            const float2 w1 = *(const float2*)(oproj_w + (size_t)(2*p+1)*CDIM + 2*L);
            t0 = fmaf(ae,w0.x,t0); t1 = fmaf(ae,w0.y,t1);
            t0 = fmaf(ao,w1.x,t0); t1 = fmaf(ao,w1.y,t1);
        }

        float z30=0,z31=0;
        #pragma unroll 4
        for (int p = 0; p < 64; ++p) {
            const float ae = rdlane(t0,p), ao = rdlane(t1,p);
            const float2 w0 = *(const float2*)(oout_w + (size_t)(2*p  )*CDIM + 2*L);
            const float2 w1 = *(const float2*)(oout_w + (size_t)(2*p+1)*CDIM + 2*L);
            z30 = fmaf(ae,w0.x,z30); z31 = fmaf(ae,w0.y,z31);
            z30 = fmaf(ao,w1.x,z30); z31 = fmaf(ao,w1.y,z31);
        }
        const float2 obv = *(const float2*)(oout_b + 2*L);
        *(float2*)(out + (size_t)tok*CDIM + 2*L) =
            make_float2(sigmoid_(z30+obv.x)*t0, sigmoid_(z31+obv.y)*t1);
    }
}

// ==================== Fallback: verified 3-kernel path ====================
__global__ __launch_bounds__(512) void k_front(
    const float* __restrict__ x, const float* __restrict__ s,
    const float* __restrict__ s_w,
    const float* __restrict__ gate_w, const float* __restrict__ gate_b,
    const float* __restrict__ skip_w,
    const float* __restrict__ q_w, const float* __restrict__ q_b,
    const float* __restrict__ k_w, const float* __restrict__ v_w,
    const float* __restrict__ pair, const float* __restrict__ pln_w,
    const float* __restrict__ pln_b, const float* __restrict__ pproj,
    float* __restrict__ qo, float* __restrict__ ko, float* __restrict__ vo,
    float* __restrict__ bias)
{
    __shared__ float act_t[CDIM][10];
    __shared__ float sn_t[CDIM][10];
    __shared__ float part[8][3][BT][CDIM];
    const int tid = threadIdx.x;
    const int bid = blockIdx.x;

    if (bid >= NTOK/BT) {
        const int idx = (bid - NTOK/BT) * 512 + tid;
        const int qg = idx >> 7;
        const int j  = idx & 127;
        const int ib = qg >> 5;
        const int qr = qg & 31;
        const int kg = (ib << 5) - PADW + j;
        float outh[HHEADS] = {0,0,0,0,0,0,0,0};
        if (kg >= 0 && kg < NTOK) {
            const float* p = pair + ((size_t)qg * NTOK + kg) * CPD;
            float buf[CPD];
            float sum = 0.f, ssq = 0.f;
            #pragma unroll
            for (int c = 0; c < CPD; c += 4) {
                const float4 t4 = *(const float4*)(p + c);
                buf[c+0]=t4.x; buf[c+1]=t4.y; buf[c+2]=t4.z; buf[c+3]=t4.w;
                sum += t4.x+t4.y+t4.z+t4.w;
                ssq += t4.x*t4.x+t4.y*t4.y+t4.z*t4.z+t4.w*t4.w;
            }
            const float m  = sum * (1.0f/CPD);
            const float vr = ssq * (1.0f/CPD) - m*m;
            const float rs = rsqrtf(vr + 1e-5f);
            #pragma unroll
            for (int c = 0; c < CPD; ++c) {
                const float y = (buf[c]-m)*rs*pln_w[c] + pln_b[c];
                #pragma unroll
                for (int h = 0; h < HHEADS; ++h)
                    outh[h] = fmaf(y, pproj[c*HHEADS+h], outh[h]);
            }
        }
        float* bb = bias + ((size_t)(ib*HHEADS)*NQW + qr)*NKW + j;
        #pragma unroll
        for (int h = 0; h < HHEADS; ++h)
            bb[(size_t)h*NQW*NKW] = outh[h];
        return;
    }

    const int tok0 = bid * BT;
    const int w = tid >> 6;
    const int L = tid & 63;
    {
        const float2 xv = *(const float2*)(x + (size_t)(tok0+w)*CDIM + 2*L);
        const float2 yv = *(const float2*)(s + (size_t)(tok0+w)*CDIM + 2*L);
        float sx = xv.x+xv.y, sxx = xv.x*xv.x+xv.y*xv.y;
        float sy = yv.x+yv.y, syy = yv.x*yv.x+yv.y*yv.y;
        #pragma unroll
        for (int m = 1; m < 64; m <<= 1) {
            sx  += __shfl_xor(sx,  m, 64);
            sxx += __shfl_xor(sxx, m, 64);
            sy  += __shfl_xor(sy,  m, 64);
            syy += __shfl_xor(syy, m, 64);
        }
        const float inv = 1.0f/128.0f;
        const float mx = sx*inv, vx = sxx*inv - mx*mx;
        const float my = sy*inv, vy = syy*inv - my*my;
        const float rx = rsqrtf(vx+1e-5f), ry = rsqrtf(vy+1e-5f);
        const float2 swv = *(const float2*)(s_w + 2*L);
        act_t[2*L][w]   = (xv.x-mx)*rx;
        act_t[2*L+1][w] = (xv.y-mx)*rx;
        sn_t[2*L][w]    = (yv.x-my)*ry*swv.x;
        sn_t[2*L+1][w]  = (yv.y-my)*ry*swv.y;
    }
    __syncthreads();

    const int i0 = w * 16;
    float snr0 = sn_t[i0 + (L>>3)][L&7];
    float snr1 = sn_t[i0 + 8 + (L>>3)][L&7];

    float ag[8][2] = {{0}}, as_[8][2] = {{0}};
    #pragma unroll
    for (int ii = 0; ii < 16; ++ii) {
        const float2 wg  = *(const float2*)(gate_w + (size_t)(i0+ii)*CDIM + 2*L);
        const float2 wsk = *(const float2*)(skip_w + (size_t)(i0+ii)*CDIM + 2*L);
        #pragma unroll
        for (int t = 0; t < 8; ++t) {
            const int v = ii*8 + t;
            const float a = rdlane((v < 64) ? snr0 : snr1, v & 63);
            ag[t][0]  = fmaf(a, wg.x,  ag[t][0]);
            ag[t][1]  = fmaf(a, wg.y,  ag[t][1]);
            as_[t][0] = fmaf(a, wsk.x, as_[t][0]);
            as_[t][1] = fmaf(a, wsk.y, as_[t][1]);
        }
    }
    #pragma unroll
    for (int t = 0; t < 8; ++t) {
        *(float2*)&part[w][0][t][2*L] = make_float2(ag[t][0],  ag[t][1]);
        *(float2*)&part[w][1][t][2*L] = make_float2(as_[t][0], as_[t][1]);
    }
    __syncthreads();

    const int j  = tid & 127;
    const int tq = tid >> 7;
    {
        float zg[2] = {0,0}, zs[2] = {0,0};
        #pragma unroll
        for (int ww = 0; ww < 8; ++ww) {
            #pragma unroll
            for (int tt = 0; tt < 2; ++tt) {
                zg[tt] += part[ww][0][2*tq+tt][j];
                zs[tt] += part[ww][1][2*tq+tt][j];
            }
        }
        const float gb = gate_b[j];
        const float2 av = *(const float2*)&act_t[j][2*tq];
        const float a2x = sigmoid_(zg[0]+gb)*av.x + zs[0];
        const float a2y = sigmoid_(zg[1]+gb)*av.y + zs[1];
        *(float2*)&sn_t[j][2*tq] = make_float2(a2x, a2y);
    }
    __syncthreads();

    float ar0 = sn_t[i0 + (L>>3)][L&7];
    float ar1 = sn_t[i0 + 8 + (L>>3)][L&7];
    float aq[8][2] = {{0}}, ak[8][2] = {{0}}, avv[8][2] = {{0}};
    #pragma unroll
    for (int ii = 0; ii < 16; ++ii) {
        const float2 wq = *(const float2*)(q_w + (size_t)(i0+ii)*CDIM + 2*L);
        const float2 wk = *(const float2*)(k_w + (size_t)(i0+ii)*CDIM + 2*L);
        const float2 wv = *(const float2*)(v_w + (size_t)(i0+ii)*CDIM + 2*L);
        #pragma unroll
        for (int t = 0; t < 8; ++t) {
            const int v = ii*8 + t;
            const float a = rdlane((v < 64) ? ar0 : ar1, v & 63);
            aq[t][0]  = fmaf(a, wq.x, aq[t][0]);
            aq[t][1]  = fmaf(a, wq.y, aq[t][1]);
            ak[t][0]  = fmaf(a, wk.x, ak[t][0]);
            ak[t][1]  = fmaf(a, wk.y, ak[t][1]);
            avv[t][0] = fmaf(a, wv.x, avv[t][0]);
            avv[t][1] = fmaf(a, wv.y, avv[t][1]);
        }
    }
    #pragma unroll
    for (int t = 0; t < 8; ++t) {
        *(float2*)&part[w][0][t][2*L] = make_float2(aq[t][0],  aq[t][1]);
        *(float2*)&part[w][1][t][2*L] = make_float2(ak[t][0],  ak[t][1]);
        *(float2*)&part[w][2][t][2*L] = make_float2(avv[t][0], avv[t][1]);
    }
    __syncthreads();
    {
        float zq[2] = {0,0}, zk[2] = {0,0}, zv[2] = {0,0};
        #pragma unroll
        for (int ww = 0; ww < 8; ++ww) {
            #pragma unroll
            for (int tt = 0; tt < 2; ++tt) {
                zq[tt] += part[ww][0][2*tq+tt][j];
                zk[tt] += part[ww][1][2*tq+tt][j];
                zv[tt] += part[ww][2][2*tq+tt][j];
            }
        }
        const float qbj = q_b[j];
        #pragma unroll
        for (int tt = 0; tt < 2; ++tt) {
            const size_t row = (size_t)(tok0 + 2*tq + tt)*CDIM + j;
            qo[row] = zq[tt] + qbj;
            ko[row] = zk[tt];
            vo[row] = zv[tt];
        }
    }
}

__global__ __launch_bounds__(256) void k_attn(
    const float* __restrict__ qi, const float* __restrict__ ki,
    const float* __restrict__ vi, const float* __restrict__ bias,
    float* __restrict__ o)
{
    __shared__ float khs[NKW*20];
    __shared__ float vts[HDIM*132];
    __shared__ float Pms[NQW*132];
    const int ib = blockIdx.x;
    const int h  = blockIdx.y;
    const int t  = threadIdx.x;

    {
        const int jr  = t >> 1;
        const int d08 = (t & 1) * 8;
        const int kg  = ib*NQW - PADW + jr;
        float4 k0 = {0,0,0,0}, k1 = {0,0,0,0};
        float4 v0 = {0,0,0,0}, v1 = {0,0,0,0};
        if (kg >= 0 && kg < NTOK) {
            const float* sk = ki + (size_t)kg*CDIM + h*HDIM + d08;
            const float* sv = vi + (size_t)kg*CDIM + h*HDIM + d08;
            k0 = *(const float4*)sk;  k1 = *(const float4*)(sk+4);
            v0 = *(const float4*)sv;  v1 = *(const float4*)(sv+4);
        }
        *(float4*)&khs[jr*20 + d08]     = k0;
        *(float4*)&khs[jr*20 + d08 + 4] = k1;
        vts[(d08+0)*132 + jr] = v0.x;
        vts[(d08+1)*132 + jr] = v0.y;
        vts[(d08+2)*132 + jr] = v0.z;
        vts[(d08+3)*132 + jr] = v0.w;
        vts[(d08+4)*132 + jr] = v1.x;
        vts[(d08+5)*132 + jr] = v1.y;
        vts[(d08+6)*132 + jr] = v1.z;
        vts[(d08+7)*132 + jr] = v1.w;
    }
    __syncthreads();

    {
        const int rp = t >> 4;
        const int ln = t & 15;
        const int q0 = 2*rp;
        float4 qv[2][4];
        #pragma unroll
        for (int i = 0; i < 2; ++i) {
            const float4* qp = (const float4*)(qi + (size_t)(ib*NQW + q0 + i)*CDIM + h*HDIM);
            #pragma unroll
            for (int dq = 0; dq < 4; ++dq) qv[i][dq] = qp[dq];
        }
        const float* br = bias + ((size_t)(ib*HHEADS + h)*NQW + q0)*NKW;
        float acc[2][8];
        #pragma unroll
        for (int m2 = 0; m2 < 8; ++m2) {
            const int k = ln + 16*m2;
            const float4 c0 = *(const float4*)&khs[k*20];
            const float4 c1 = *(const float4*)&khs[k*20 + 4];
            const float4 c2 = *(const float4*)&khs[k*20 + 8];
            const float4 c3 = *(const float4*)&khs[k*20 + 12];
            #pragma unroll
            for (int i = 0; i < 2; ++i) {
                float sdot = qv[i][0].x*c0.x;
                sdot = fmaf(qv[i][0].y, c0.y, sdot);
                sdot = fmaf(qv[i][0].z, c0.z, sdot);
                sdot = fmaf(qv[i][0].w, c0.w, sdot);
                sdot = fmaf(qv[i][1].x, c1.x, sdot);
                sdot = fmaf(qv[i][1].y, c1.y, sdot);
                sdot = fmaf(qv[i][1].z, c1.z, sdot);
                sdot = fmaf(qv[i][1].w, c1.w, sdot);
                sdot = fmaf(qv[i][2].x, c2.x, sdot);
                sdot = fmaf(qv[i][2].y, c2.y, sdot);
                sdot = fmaf(qv[i][2].z, c2.z, sdot);
                sdot = fmaf(qv[i][2].w, c2.w, sdot);
                sdot = fmaf(qv[i][3].x, c3.x, sdot);
                sdot = fmaf(qv[i][3].y, c3.y, sdot);
                sdot = fmaf(qv[i][3].z, c3.z, sdot);
                sdot = fmaf(qv[i][3].w, c3.w, sdot);
                acc[i][m2] = sdot*0.25f + br[(size_t)i*NKW + k];
            }
        }
        #pragma unroll
        for (int i = 0; i < 2; ++i) {
            float mx = acc[i][0];
            #pragma unroll
            for (int m2 = 1; m2 < 8; ++m2) mx = fmaxf(mx, acc[i][m2]);
            mx = fmaxf(mx, __shfl_xor(mx, 1, 64));
            mx = fmaxf(mx, __shfl_xor(mx, 2, 64));
            mx = fmaxf(mx, __shfl_xor(mx, 4, 64));
            mx = fmaxf(mx, __shfl_xor(mx, 8, 64));
            float sm = 0.f;
            #pragma unroll
            for (int m2 = 0; m2 < 8; ++m2) { acc[i][m2] = __expf(acc[i][m2]-mx); sm += acc[i][m2]; }
            sm += __shfl_xor(sm, 1, 64);
            sm += __shfl_xor(sm, 2, 64);
            sm += __shfl_xor(sm, 4, 64);
            sm += __shfl_xor(sm, 8, 64);
            const float invs = 1.0f / sm;
            #pragma unroll
            for (int m2 = 0; m2 < 8; ++m2)
                Pms[(q0+i)*132 + ln + 16*m2] = acc[i][m2]*invs;
        }
    }
    __syncthreads();

    {
        const int qr = t >> 3, d0 = t & 7;
        const float* pr  = &Pms[qr*132];
        const float* vp0 = &vts[d0*132];
        const float* vp1 = &vts[(d0+8)*132];
        float a0 = 0.f, a1 = 0.f;
        #pragma unroll
        for (int k4 = 0; k4 < 32; ++k4) {
            const float4 pm = *(const float4*)(pr  + 4*k4);
            const float4 u0 = *(const float4*)(vp0 + 4*k4);
            const float4 u1 = *(const float4*)(vp1 + 4*k4);
            a0 = fmaf(pm.x, u0.x, a0); a0 = fmaf(pm.y, u0.y, a0);
            a0 = fmaf(pm.z, u0.z, a0); a0 = fmaf(pm.w, u0.w, a0);
            a1 = fmaf(pm.x, u1.x, a1); a1 = fmaf(pm.y, u1.y, a1);
            a1 = fmaf(pm.z, u1.z, a1); a1 = fmaf(pm.w, u1.w, a1);
        }
        float* dst = o + (size_t)(ib*NQW + qr)*CDIM + h*HDIM;
        dst[d0]   = a0;
        dst[d0+8] = a1;
    }
}

__global__ __launch_bounds__(512) void k_back(
    const float* __restrict__ oin, const float* __restrict__ gate_w,
    const float* __restrict__ proj_w, const float* __restrict__ out_w,
    const float* __restrict__ out_b, float* __restrict__ out)
{
    __shared__ float b0_t[CDIM][10];
    __shared__ float b1_t[CDIM][10];
    __shared__ float part[8][BT][CDIM];
    const int tid = threadIdx.x;
    const int tok0 = blockIdx.x * BT;
    const int w = tid >> 6, L = tid & 63;
    const int j = tid & 127, tq = tid >> 7;

    {
        const float2 ov = *(const float2*)(oin + (size_t)tok0*CDIM + 2*tid);
        const int e = 2*tid, c = e & 127, t = e >> 7;
        b0_t[c][t]   = ov.x;
        b0_t[c+1][t] = ov.y;
    }
    __syncthreads();

    const int i0 = w * 16;

    {
        const float r0 = b0_t[i0 + (L>>3)][L&7];
        const float r1 = b0_t[i0 + 8 + (L>>3)][L&7];
        float acc[8][2] = {{0}};
        #pragma unroll
        for (int ii = 0; ii < 16; ++ii) {
            const float2 wv = *(const float2*)(gate_w + (size_t)(i0+ii)*CDIM + 2*L);
            #pragma unroll
            for (int t = 0; t < 8; ++t) {
                const int v = ii*8 + t;
                const float a = rdlane((v < 64) ? r0 : r1, v & 63);
                acc[t][0] = fmaf(a, wv.x, acc[t][0]);
                acc[t][1] = fmaf(a, wv.y, acc[t][1]);
            }
        }
        #pragma unroll
        for (int t = 0; t < 8; ++t)
            *(float2*)&part[w][t][2*L] = make_float2(acc[t][0], acc[t][1]);
    }
    __syncthreads();
    {
        float z[2] = {0,0};
        #pragma unroll
        for (int ww = 0; ww < 8; ++ww) {
            z[0] += part[ww][2*tq][j];
            z[1] += part[ww][2*tq+1][j];
        }
        const float2 ov = *(const float2*)&b0_t[j][2*tq];
        *(float2*)&b1_t[j][2*tq] = make_float2(sigmoid_(z[0])*ov.x, sigmoid_(z[1])*ov.y);
    }
    __syncthreads();

    {
        const float r0 = b1_t[i0 + (L>>3)][L&7];
        const float r1 = b1_t[i0 + 8 + (L>>3)][L&7];
        float acc[8][2] = {{0}};
        #pragma unroll
        for (int ii = 0; ii < 16; ++ii) {
            const float2 wv = *(const float2*)(proj_w + (size_t)(i0+ii)*CDIM + 2*L);
            #pragma unroll
            for (int t = 0; t < 8; ++t) {
                const int v = ii*8 + t;
                const float a = rdlane((v < 64) ? r0 : r1, v & 63);
                acc[t][0] = fmaf(a, wv.x, acc[t][0]);
                acc[t][1] = fmaf(a, wv.y, acc[t][1]);
            }
        }
        #pragma unroll
        for (int t = 0; t < 8; ++t)
            *(float2*)&part[w][t][2*L] = make_float2(acc[t][0], acc[t][1]);
    }
    __syncthreads();
    float t2v[2];
    {
        float z[2] = {0,0};
        #pragma unroll
        for (int ww = 0; ww < 8; ++ww) {
            z[0] += part[ww][2*tq][j];
            z[1] += part[ww][2*tq+1][j];
        }
        t2v[0] = z[0]; t2v[1] = z[1];
        *(float2*)&b0_t[j][2*tq] = make_float2(z[0], z[1]);
    }
    __syncthreads();

    {
        const float r0 = b0_t[i0 + (L>>3)][L&7];
        const float r1 = b0_t[i0 + 8 + (L>>3)][L&7];
        float acc[8][2] = {{0}};
        #pragma unroll
        for (int ii = 0; ii < 16; ++ii) {
            const float2 wv = *(const float2*)(out_w + (size_t)(i0+ii)*CDIM + 2*L);
            #pragma unroll
            for (int t = 0; t < 8; ++t) {
                const int v = ii*8 + t;
                const float a = rdlane((v < 64) ? r0 : r1, v & 63);
                acc[t][0] = fmaf(a, wv.x, acc[t][0]);
                acc[t][1] = fmaf(a, wv.y, acc[t][1]);
            }
        }
        #pragma unroll
        for (int t = 0; t < 8; ++t)
            *(float2*)&part[w][t][2*L] = make_float2(acc[t][0], acc[t][1]);
    }
    __syncthreads();
    {
        float z[2] = {0,0};
        #pragma unroll
        for (int ww = 0; ww < 8; ++ww) {
            z[0] += part[ww][2*tq][j];
            z[1] += part[ww][2*tq+1][j];
        }
        const float ob = out_b[j];
        out[(size_t)(tok0 + 2*tq)*CDIM + j]     = sigmoid_(z[0]+ob)*t2v[0];
        out[(size_t)(tok0 + 2*tq + 1)*CDIM + j] = sigmoid_(z[1]+ob)*t2v[1];
    }
}

extern "C" void kernel_launch(void* const* d_in, const int* in_sizes, int n_in,
                              void* d_out, int out_size, void* d_ws, size_t ws_size,
                              hipStream_t stream) {
    (void)in_sizes; (void)n_in; (void)out_size; (void)ws_size;
    const float* x           = (const float*)d_in[0];
    const float* s           = (const float*)d_in[1];
    const float* pair        = (const float*)d_in[2];
    const float* adaln_s_w   = (const float*)d_in[3];
    const float* adaln_gate_w= (const float*)d_in[4];
    const float* adaln_gate_b= (const float*)d_in[5];
    const float* adaln_skip_w= (const float*)d_in[6];
    const float* q_w         = (const float*)d_in[7];
    const float* q_b         = (const float*)d_in[8];
    const float* k_w         = (const float*)d_in[9];
    const float* v_w         = (const float*)d_in[10];
    const float* pair_ln_w   = (const float*)d_in[11];
    const float* pair_ln_b   = (const float*)d_in[12];
    const float* pair_proj_w = (const float*)d_in[13];
    const float* gate_w      = (const float*)d_in[14];
    const float* attn_proj_w = (const float*)d_in[15];
    const float* out_w       = (const float*)d_in[16];
    const float* out_b       = (const float*)d_in[17];
    float* out = (float*)d_out;

    float* ws = (float*)d_ws;
    float* q_ws    = ws;                 // 2048*128
    float* k_ws    = ws + 262144;
    float* v_ws    = ws + 524288;
    float* o_ws    = ws + 786432;
    float* bias_ws = ws + 1048576;       // 64*8*32*128

    void* args[] = {
        (void*)&x, (void*)&s, (void*)&adaln_s_w, (void*)&adaln_gate_w,
        (void*)&adaln_gate_b, (void*)&adaln_skip_w, (void*)&q_w, (void*)&q_b,
        (void*)&k_w, (void*)&v_w, (void*)&pair, (void*)&pair_ln_w,
        (void*)&pair_ln_b, (void*)&pair_proj_w, (void*)&gate_w,
        (void*)&attn_proj_w, (void*)&out_w, (void*)&out_b,
        (void*)&q_ws, (void*)&k_ws, (void*)&v_ws, (void*)&o_ws,
        (void*)&bias_ws, (void*)&out
    };
    hipError_t err = hipLaunchCooperativeKernel((const void*)k_fused,
                                                dim3(256), dim3(512),
                                                args, 0, stream);
    if (err != hipSuccess) {
        (void)hipGetLastError();   // clear sticky error, use verified 3-kernel path
        k_front<<<NTOK/BT + (NTOK*NKW)/512, 512, 0, stream>>>(
            x, s, adaln_s_w, adaln_gate_w, adaln_gate_b, adaln_skip_w,
            q_w, q_b, k_w, v_w, pair, pair_ln_w, pair_ln_b, pair_proj_w,
            q_ws, k_ws, v_ws, bias_ws);
        k_attn<<<dim3(NTOK/NQW, HHEADS), 256, 0, stream>>>(q_ws, k_ws, v_ws, bias_ws, o_ws);
        k_back<<<NTOK/BT, 512, 0, stream>>>(o_ws, gate_w, attn_proj_w, out_w, out_b, out);
    }
}

// Round 3
// 34.146 us; speedup vs baseline: 4.3955x; 4.3955x over previous
//
#include <hip/hip_runtime.h>
#include <math.h>

#define NTOK 2048
#define CDIM 128
#define HHEADS 8
#define HDIM 16
#define NQW 32
#define NKW 128
#define PADW 48
#define CPD 16
#define BT 8

__device__ __forceinline__ float sigmoid_(float z){ return 1.0f/(1.0f+__expf(-z)); }
__device__ __forceinline__ float rdlane(float v, int l){
    return __int_as_float(__builtin_amdgcn_readlane(__float_as_int(v), l));
}

// ============ Kernel 1: AdaLN+QKV (blocks 0..255) + pair bias (blocks 256..511) ============
// LDS slimmed to 74 KB (2-slot partials, reused q/k then v) -> 2 blocks/CU, so all
// 512 blocks fit in ONE dispatch round; pair blocks (HBM-latency-bound) co-reside
// with QKV blocks (VALU-bound) and hide each other.
__global__ __launch_bounds__(512, 4) void k_front(
    const float* __restrict__ x, const float* __restrict__ s,
    const float* __restrict__ s_w,
    const float* __restrict__ gate_w, const float* __restrict__ gate_b,
    const float* __restrict__ skip_w,
    const float* __restrict__ q_w, const float* __restrict__ q_b,
    const float* __restrict__ k_w, const float* __restrict__ v_w,
    const float* __restrict__ pair, const float* __restrict__ pln_w,
    const float* __restrict__ pln_b, const float* __restrict__ pproj,
    float* __restrict__ qo, float* __restrict__ ko, float* __restrict__ vo,
    float* __restrict__ bias)
{
    __shared__ float act_t[CDIM][10];          // [channel][token], padded
    __shared__ float sn_t[CDIM][10];           // sn, later a2
    __shared__ float part[8][2][BT][CDIM];     // 64 KB partials (2 slots, reused)
    const int tid = threadIdx.x;
    const int bid = blockIdx.x;

    if (bid >= NTOK/BT) {
        // ---------------- pair-bias path: 2 items per thread ----------------
        #pragma unroll
        for (int rep = 0; rep < 2; ++rep) {
            const int idx = (bid - NTOK/BT) * 1024 + rep*512 + tid;   // [0, 2048*128)
            const int qg = idx >> 7;
            const int j  = idx & 127;
            const int ib = qg >> 5;
            const int qr = qg & 31;
            const int kg = (ib << 5) - PADW + j;
            float outh[HHEADS] = {0,0,0,0,0,0,0,0};
            if (kg >= 0 && kg < NTOK) {
                const float* p = pair + ((size_t)qg * NTOK + kg) * CPD;
                float buf[CPD];
                float sum = 0.f, ssq = 0.f;
                #pragma unroll
                for (int c = 0; c < CPD; c += 4) {
                    const float4 t4 = *(const float4*)(p + c);
                    buf[c+0]=t4.x; buf[c+1]=t4.y; buf[c+2]=t4.z; buf[c+3]=t4.w;
                    sum += t4.x+t4.y+t4.z+t4.w;
                    ssq += t4.x*t4.x+t4.y*t4.y+t4.z*t4.z+t4.w*t4.w;
                }
                const float m  = sum * (1.0f/CPD);
                const float vr = ssq * (1.0f/CPD) - m*m;
                const float rs = rsqrtf(vr + 1e-5f);
                #pragma unroll
                for (int c = 0; c < CPD; ++c) {
                    const float y = (buf[c]-m)*rs*pln_w[c] + pln_b[c];
                    #pragma unroll
                    for (int h = 0; h < HHEADS; ++h)
                        outh[h] = fmaf(y, pproj[c*HHEADS+h], outh[h]);
                }
            }
            float* bb = bias + ((size_t)(ib*HHEADS)*NQW + qr)*NKW + j;
            #pragma unroll
            for (int h = 0; h < HHEADS; ++h)
                bb[(size_t)h*NQW*NKW] = outh[h];
        }
        return;
    }

    // ---------------- AdaLN + QKV path ----------------
    const int tok0 = bid * BT;
    const int w = tid >> 6;      // wave 0..7
    const int L = tid & 63;

    // LN: wave w -> token w; lane L -> channels 2L, 2L+1
    {
        const float2 xv = *(const float2*)(x + (size_t)(tok0+w)*CDIM + 2*L);
        const float2 yv = *(const float2*)(s + (size_t)(tok0+w)*CDIM + 2*L);
        float sx = xv.x+xv.y, sxx = xv.x*xv.x+xv.y*xv.y;
        float sy = yv.x+yv.y, syy = yv.x*yv.x+yv.y*yv.y;
        #pragma unroll
        for (int m = 1; m < 64; m <<= 1) {
            sx  += __shfl_xor(sx,  m, 64);
            sxx += __shfl_xor(sxx, m, 64);
            sy  += __shfl_xor(sy,  m, 64);
            syy += __shfl_xor(syy, m, 64);
        }
        const float inv = 1.0f/128.0f;
        const float mx = sx*inv, vx = sxx*inv - mx*mx;
        const float my = sy*inv, vy = syy*inv - my*my;
        const float rx = rsqrtf(vx+1e-5f), ry = rsqrtf(vy+1e-5f);
        const float2 swv = *(const float2*)(s_w + 2*L);
        act_t[2*L][w]   = (xv.x-mx)*rx;
        act_t[2*L+1][w] = (xv.y-mx)*rx;
        sn_t[2*L][w]    = (yv.x-my)*ry*swv.x;
        sn_t[2*L+1][w]  = (yv.y-my)*ry*swv.y;
    }
    __syncthreads();                                   // (1)

    const int i0 = w * 16;
    // readlane layout: reg r, lane l holds value v=64r+l -> (ii=v>>3, t=v&7)
    float snr0 = sn_t[i0 + (L>>3)][L&7];
    float snr1 = sn_t[i0 + 8 + (L>>3)][L&7];

    // ---- gate/skip matvec over i-chunk ----
    float ag[8][2] = {{0}}, as_[8][2] = {{0}};
    #pragma unroll
    for (int ii = 0; ii < 16; ++ii) {
        const float2 wg  = *(const float2*)(gate_w + (size_t)(i0+ii)*CDIM + 2*L);
        const float2 wsk = *(const float2*)(skip_w + (size_t)(i0+ii)*CDIM + 2*L);
        #pragma unroll
        for (int t = 0; t < 8; ++t) {
            const int v = ii*8 + t;
            const float a = rdlane((v < 64) ? snr0 : snr1, v & 63);
            ag[t][0]  = fmaf(a, wg.x,  ag[t][0]);
            ag[t][1]  = fmaf(a, wg.y,  ag[t][1]);
            as_[t][0] = fmaf(a, wsk.x, as_[t][0]);
            as_[t][1] = fmaf(a, wsk.y, as_[t][1]);
        }
    }
    #pragma unroll
    for (int t = 0; t < 8; ++t) {
        *(float2*)&part[w][0][t][2*L] = make_float2(ag[t][0],  ag[t][1]);
        *(float2*)&part[w][1][t][2*L] = make_float2(as_[t][0], as_[t][1]);
    }
    __syncthreads();                                   // (2)

    const int j  = tid & 127;
    const int tq = tid >> 7;
    // reduce + a2 = sigmoid(zg+b)*a + zs ; write a2 into sn_t
    {
        float zg[2] = {0,0}, zs[2] = {0,0};
        #pragma unroll
        for (int ww = 0; ww < 8; ++ww) {
            #pragma unroll
            for (int tt = 0; tt < 2; ++tt) {
                zg[tt] += part[ww][0][2*tq+tt][j];
                zs[tt] += part[ww][1][2*tq+tt][j];
            }
        }
        const float gb = gate_b[j];
        const float2 av = *(const float2*)&act_t[j][2*tq];
        const float a2x = sigmoid_(zg[0]+gb)*av.x + zs[0];
        const float a2y = sigmoid_(zg[1]+gb)*av.y + zs[1];
        *(float2*)&sn_t[j][2*tq] = make_float2(a2x, a2y);
    }
    __syncthreads();                                   // (3)

    // ---- q/k/v matvec over i-chunk ----
    float ar0 = sn_t[i0 + (L>>3)][L&7];
    float ar1 = sn_t[i0 + 8 + (L>>3)][L&7];
    float aq[8][2] = {{0}}, ak[8][2] = {{0}}, avv[8][2] = {{0}};
    #pragma unroll
    for (int ii = 0; ii < 16; ++ii) {
        const float2 wq = *(const float2*)(q_w + (size_t)(i0+ii)*CDIM + 2*L);
        const float2 wk = *(const float2*)(k_w + (size_t)(i0+ii)*CDIM + 2*L);
        const float2 wv = *(const float2*)(v_w + (size_t)(i0+ii)*CDIM + 2*L);
        #pragma unroll
        for (int t = 0; t < 8; ++t) {
            const int v = ii*8 + t;
            const float a = rdlane((v < 64) ? ar0 : ar1, v & 63);
            aq[t][0]  = fmaf(a, wq.x, aq[t][0]);
            aq[t][1]  = fmaf(a, wq.y, aq[t][1]);
            ak[t][0]  = fmaf(a, wk.x, ak[t][0]);
            ak[t][1]  = fmaf(a, wk.y, ak[t][1]);
            avv[t][0] = fmaf(a, wv.x, avv[t][0]);
            avv[t][1] = fmaf(a, wv.y, avv[t][1]);
        }
    }
    // q/k use the two slots first
    #pragma unroll
    for (int t = 0; t < 8; ++t) {
        *(float2*)&part[w][0][t][2*L] = make_float2(aq[t][0], aq[t][1]);
        *(float2*)&part[w][1][t][2*L] = make_float2(ak[t][0], ak[t][1]);
    }
    __syncthreads();                                   // (4)
    {
        float zq[2] = {0,0}, zk[2] = {0,0};
        #pragma unroll
        for (int ww = 0; ww < 8; ++ww) {
            #pragma unroll
            for (int tt = 0; tt < 2; ++tt) {
                zq[tt] += part[ww][0][2*tq+tt][j];
                zk[tt] += part[ww][1][2*tq+tt][j];
            }
        }
        const float qbj = q_b[j];
        #pragma unroll
        for (int tt = 0; tt < 2; ++tt) {
            const size_t row = (size_t)(tok0 + 2*tq + tt)*CDIM + j;
            qo[row] = zq[tt] + qbj;
            ko[row] = zk[tt];
        }
    }
    __syncthreads();                                   // (5) readers done before reuse
    #pragma unroll
    for (int t = 0; t < 8; ++t)
        *(float2*)&part[w][0][t][2*L] = make_float2(avv[t][0], avv[t][1]);
    __syncthreads();                                   // (6)
    {
        float zv[2] = {0,0};
        #pragma unroll
        for (int ww = 0; ww < 8; ++ww) {
            #pragma unroll
            for (int tt = 0; tt < 2; ++tt)
                zv[tt] += part[ww][0][2*tq+tt][j];
        }
        #pragma unroll
        for (int tt = 0; tt < 2; ++tt)
            vo[(size_t)(tok0 + 2*tq + tt)*CDIM + j] = zv[tt];
    }
}

// ============ Kernel 2: local-window attention — b128-native LDS layouts (verified R0) ============
__global__ __launch_bounds__(256) void k_attn(
    const float* __restrict__ qi, const float* __restrict__ ki,
    const float* __restrict__ vi, const float* __restrict__ bias,
    float* __restrict__ o)
{
    __shared__ float khs[NKW*20];        // 10.2 KB
    __shared__ float vts[HDIM*132];      // 8.4 KB  (V^T)
    __shared__ float Pms[NQW*132];       // 16.9 KB
    const int ib = blockIdx.x;
    const int h  = blockIdx.y;
    const int t  = threadIdx.x;

    {   // stage: K row-major padded, V transposed
        const int jr  = t >> 1;
        const int d08 = (t & 1) * 8;
        const int kg  = ib*NQW - PADW + jr;
        float4 k0 = {0,0,0,0}, k1 = {0,0,0,0};
        float4 v0 = {0,0,0,0}, v1 = {0,0,0,0};
        if (kg >= 0 && kg < NTOK) {
            const float* sk = ki + (size_t)kg*CDIM + h*HDIM + d08;
            const float* sv = vi + (size_t)kg*CDIM + h*HDIM + d08;
            k0 = *(const float4*)sk;  k1 = *(const float4*)(sk+4);
            v0 = *(const float4*)sv;  v1 = *(const float4*)(sv+4);
        }
        *(float4*)&khs[jr*20 + d08]     = k0;
        *(float4*)&khs[jr*20 + d08 + 4] = k1;
        vts[(d08+0)*132 + jr] = v0.x;
        vts[(d08+1)*132 + jr] = v0.y;
        vts[(d08+2)*132 + jr] = v0.z;
        vts[(d08+3)*132 + jr] = v0.w;
        vts[(d08+4)*132 + jr] = v1.x;
        vts[(d08+5)*132 + jr] = v1.y;
        vts[(d08+6)*132 + jr] = v1.z;
        vts[(d08+7)*132 + jr] = v1.w;
    }
    __syncthreads();

    {   // QK^T + bias + softmax: thread = 2 q-rows x 8 k-cols
        const int rp = t >> 4;
        const int ln = t & 15;
        const int q0 = 2*rp;
        float4 qv[2][4];
        #pragma unroll
        for (int i = 0; i < 2; ++i) {
            const float4* qp = (const float4*)(qi + (size_t)(ib*NQW + q0 + i)*CDIM + h*HDIM);
            #pragma unroll
            for (int dq = 0; dq < 4; ++dq) qv[i][dq] = qp[dq];
        }
        const float* br = bias + ((size_t)(ib*HHEADS + h)*NQW + q0)*NKW;
        float acc[2][8];
        #pragma unroll
        for (int m2 = 0; m2 < 8; ++m2) {
            const int k = ln + 16*m2;
            const float4 c0 = *(const float4*)&khs[k*20];
            const float4 c1 = *(const float4*)&khs[k*20 + 4];
            const float4 c2 = *(const float4*)&khs[k*20 + 8];
            const float4 c3 = *(const float4*)&khs[k*20 + 12];
            #pragma unroll
            for (int i = 0; i < 2; ++i) {
                float sdot = qv[i][0].x*c0.x;
                sdot = fmaf(qv[i][0].y, c0.y, sdot);
                sdot = fmaf(qv[i][0].z, c0.z, sdot);
                sdot = fmaf(qv[i][0].w, c0.w, sdot);
                sdot = fmaf(qv[i][1].x, c1.x, sdot);
                sdot = fmaf(qv[i][1].y, c1.y, sdot);
                sdot = fmaf(qv[i][1].z, c1.z, sdot);
                sdot = fmaf(qv[i][1].w, c1.w, sdot);
                sdot = fmaf(qv[i][2].x, c2.x, sdot);
                sdot = fmaf(qv[i][2].y, c2.y, sdot);
                sdot = fmaf(qv[i][2].z, c2.z, sdot);
                sdot = fmaf(qv[i][2].w, c2.w, sdot);
                sdot = fmaf(qv[i][3].x, c3.x, sdot);
                sdot = fmaf(qv[i][3].y, c3.y, sdot);
                sdot = fmaf(qv[i][3].z, c3.z, sdot);
                sdot = fmaf(qv[i][3].w, c3.w, sdot);
                acc[i][m2] = sdot*0.25f + br[(size_t)i*NKW + k];
            }
        }
        #pragma unroll
        for (int i = 0; i < 2; ++i) {
            float mx = acc[i][0];
            #pragma unroll
            for (int m2 = 1; m2 < 8; ++m2) mx = fmaxf(mx, acc[i][m2]);
            mx = fmaxf(mx, __shfl_xor(mx, 1, 64));
            mx = fmaxf(mx, __shfl_xor(mx, 2, 64));
            mx = fmaxf(mx, __shfl_xor(mx, 4, 64));
            mx = fmaxf(mx, __shfl_xor(mx, 8, 64));
            float sm = 0.f;
            #pragma unroll
            for (int m2 = 0; m2 < 8; ++m2) { acc[i][m2] = __expf(acc[i][m2]-mx); sm += acc[i][m2]; }
            sm += __shfl_xor(sm, 1, 64);
            sm += __shfl_xor(sm, 2, 64);
            sm += __shfl_xor(sm, 4, 64);
            sm += __shfl_xor(sm, 8, 64);
            const float invs = 1.0f / sm;
            #pragma unroll
            for (int m2 = 0; m2 < 8; ++m2)
                Pms[(q0+i)*132 + ln + 16*m2] = acc[i][m2]*invs;
        }
    }
    __syncthreads();

    {   // PV: thread = (qr, d0); k-vectorized b128
        const int qr = t >> 3, d0 = t & 7;
        const float* pr  = &Pms[qr*132];
        const float* vp0 = &vts[d0*132];
        const float* vp1 = &vts[(d0+8)*132];
        float a0 = 0.f, a1 = 0.f;
        #pragma unroll
        for (int k4 = 0; k4 < 32; ++k4) {
            const float4 pm = *(const float4*)(pr  + 4*k4);
            const float4 u0 = *(const float4*)(vp0 + 4*k4);
            const float4 u1 = *(const float4*)(vp1 + 4*k4);
            a0 = fmaf(pm.x, u0.x, a0); a0 = fmaf(pm.y, u0.y, a0);
            a0 = fmaf(pm.z, u0.z, a0); a0 = fmaf(pm.w, u0.w, a0);
            a1 = fmaf(pm.x, u1.x, a1); a1 = fmaf(pm.y, u1.y, a1);
            a1 = fmaf(pm.z, u1.z, a1); a1 = fmaf(pm.w, u1.w, a1);
        }
        float* dst = o + (size_t)(ib*NQW + qr)*CDIM + h*HDIM;
        dst[d0]   = a0;
        dst[d0+8] = a1;
    }
}

// ============ Kernel 3: output gating stack (verified) ============
__global__ __launch_bounds__(512) void k_back(
    const float* __restrict__ oin, const float* __restrict__ gate_w,
    const float* __restrict__ proj_w, const float* __restrict__ out_w,
    const float* __restrict__ out_b, float* __restrict__ out)
{
    __shared__ float b0_t[CDIM][10];   // o, later t2
    __shared__ float b1_t[CDIM][10];   // gated
    __shared__ float part[8][BT][CDIM];
    const int tid = threadIdx.x;
    const int tok0 = blockIdx.x * BT;
    const int w = tid >> 6, L = tid & 63;
    const int j = tid & 127, tq = tid >> 7;

    {   // load o tile into [channel][token] layout
        const float2 ov = *(const float2*)(oin + (size_t)tok0*CDIM + 2*tid);
        const int e = 2*tid, c = e & 127, t = e >> 7;
        b0_t[c][t]   = ov.x;
        b0_t[c+1][t] = ov.y;
    }
    __syncthreads();

    const int i0 = w * 16;

    // ---- phase A: z = o @ gate_w ----
    {
        const float r0 = b0_t[i0 + (L>>3)][L&7];
        const float r1 = b0_t[i0 + 8 + (L>>3)][L&7];
        float acc[8][2] = {{0}};
        #pragma unroll
        for (int ii = 0; ii < 16; ++ii) {
            const float2 wv = *(const float2*)(gate_w + (size_t)(i0+ii)*CDIM + 2*L);
            #pragma unroll
            for (int t = 0; t < 8; ++t) {
                const int v = ii*8 + t;
                const float a = rdlane((v < 64) ? r0 : r1, v & 63);
                acc[t][0] = fmaf(a, wv.x, acc[t][0]);
                acc[t][1] = fmaf(a, wv.y, acc[t][1]);
            }
        }
        #pragma unroll
        for (int t = 0; t < 8; ++t)
            *(float2*)&part[w][t][2*L] = make_float2(acc[t][0], acc[t][1]);
    }
    __syncthreads();
    {   // reduce; g = sigmoid(z) * o -> b1_t
        float z[2] = {0,0};
        #pragma unroll
        for (int ww = 0; ww < 8; ++ww) {
            z[0] += part[ww][2*tq][j];
            z[1] += part[ww][2*tq+1][j];
        }
        const float2 ov = *(const float2*)&b0_t[j][2*tq];
        *(float2*)&b1_t[j][2*tq] = make_float2(sigmoid_(z[0])*ov.x, sigmoid_(z[1])*ov.y);
    }
    __syncthreads();

    // ---- phase B: t2 = g @ proj_w ----
    {
        const float r0 = b1_t[i0 + (L>>3)][L&7];
        const float r1 = b1_t[i0 + 8 + (L>>3)][L&7];
        float acc[8][2] = {{0}};
        #pragma unroll
        for (int ii = 0; ii < 16; ++ii) {
            const float2 wv = *(const float2*)(proj_w + (size_t)(i0+ii)*CDIM + 2*L);
            #pragma unroll
            for (int t = 0; t < 8; ++t) {
                const int v = ii*8 + t;
                const float a = rdlane((v < 64) ? r0 : r1, v & 63);
                acc[t][0] = fmaf(a, wv.x, acc[t][0]);
                acc[t][1] = fmaf(a, wv.y, acc[t][1]);
            }
        }
        #pragma unroll
        for (int t = 0; t < 8; ++t)
            *(float2*)&part[w][t][2*L] = make_float2(acc[t][0], acc[t][1]);
    }
    __syncthreads();
    float t2v[2];
    {   // reduce; keep t2 in regs, stash into b0_t for phase-C readlane source
        float z[2] = {0,0};
        #pragma unroll
        for (int ww = 0; ww < 8; ++ww) {
            z[0] += part[ww][2*tq][j];
            z[1] += part[ww][2*tq+1][j];
        }
        t2v[0] = z[0]; t2v[1] = z[1];
        *(float2*)&b0_t[j][2*tq] = make_float2(z[0], z[1]);
    }
    __syncthreads();

    // ---- phase C: z3 = t2 @ out_w ; out = sigmoid(z3+b)*t2 ----
    {
        const float r0 = b0_t[i0 + (L>>3)][L&7];
        const float r1 = b0_t[i0 + 8 + (L>>3)][L&7];
        float acc[8][2] = {{0}};
        #pragma unroll
        for (int ii = 0; ii < 16; ++ii) {
            const float2 wv = *(const float2*)(out_w + (size_t)(i0+ii)*CDIM + 2*L);
            #pragma unroll
            for (int t = 0; t < 8; ++t) {
                const int v = ii*8 + t;
                const float a = rdlane((v < 64) ? r0 : r1, v & 63);
                acc[t][0] = fmaf(a, wv.x, acc[t][0]);
                acc[t][1] = fmaf(a, wv.y, acc[t][1]);
            }
        }
        #pragma unroll
        for (int t = 0; t < 8; ++t)
            *(float2*)&part[w][t][2*L] = make_float2(acc[t][0], acc[t][1]);
    }
    __syncthreads();
    {
        float z[2] = {0,0};
        #pragma unroll
        for (int ww = 0; ww < 8; ++ww) {
            z[0] += part[ww][2*tq][j];
            z[1] += part[ww][2*tq+1][j];
        }
        const float ob = out_b[j];
        out[(size_t)(tok0 + 2*tq)*CDIM + j]     = sigmoid_(z[0]+ob)*t2v[0];
        out[(size_t)(tok0 + 2*tq + 1)*CDIM + j] = sigmoid_(z[1]+ob)*t2v[1];
    }
}

extern "C" void kernel_launch(void* const* d_in, const int* in_sizes, int n_in,
                              void* d_out, int out_size, void* d_ws, size_t ws_size,
                              hipStream_t stream) {
    (void)in_sizes; (void)n_in; (void)out_size; (void)ws_size;
    const float* x           = (const float*)d_in[0];
    const float* s           = (const float*)d_in[1];
    const float* pair        = (const float*)d_in[2];
    const float* adaln_s_w   = (const float*)d_in[3];
    const float* adaln_gate_w= (const float*)d_in[4];
    const float* adaln_gate_b= (const float*)d_in[5];
    const float* adaln_skip_w= (const float*)d_in[6];
    const float* q_w         = (const float*)d_in[7];
    const float* q_b         = (const float*)d_in[8];
    const float* k_w         = (const float*)d_in[9];
    const float* v_w         = (const float*)d_in[10];
    const float* pair_ln_w   = (const float*)d_in[11];
    const float* pair_ln_b   = (const float*)d_in[12];
    const float* pair_proj_w = (const float*)d_in[13];
    const float* gate_w      = (const float*)d_in[14];
    const float* attn_proj_w = (const float*)d_in[15];
    const float* out_w       = (const float*)d_in[16];
    const float* out_b       = (const float*)d_in[17];
    float* out = (float*)d_out;

    float* ws = (float*)d_ws;
    float* q_ws    = ws;                 // 2048*128
    float* k_ws    = ws + 262144;
    float* v_ws    = ws + 524288;
    float* o_ws    = ws + 786432;
    float* bias_ws = ws + 1048576;       // 64*8*32*128

    // 256 QKV blocks + 256 pair-bias blocks in one launch (one dispatch round at 2 blk/CU)
    k_front<<<NTOK/BT + (NTOK*NKW)/1024, 512, 0, stream>>>(
        x, s, adaln_s_w, adaln_gate_w, adaln_gate_b, adaln_skip_w,
        q_w, q_b, k_w, v_w, pair, pair_ln_w, pair_ln_b, pair_proj_w,
        q_ws, k_ws, v_ws, bias_ws);
    k_attn<<<dim3(NTOK/NQW, HHEADS), 256, 0, stream>>>(q_ws, k_ws, v_ws, bias_ws, o_ws);
    k_back<<<NTOK/BT, 512, 0, stream>>>(o_ws, gate_w, attn_proj_w, out_w, out_b, out);
}